// Round 2
// baseline (732.892 us; speedup 1.0000x reference)
//
#include <hip/hip_runtime.h>
#include <math.h>

// B=64 T=50 V=32000 E=64 DH=128 H=8 M=256 ; rows R = B*T = 3200
#define T_ 50
#define R_ 3200

using u16 = unsigned short;
typedef __attribute__((ext_vector_type(8))) __bf16 bf16x8;
typedef __attribute__((ext_vector_type(4))) float f32x4;

__device__ __forceinline__ float bf2f(u16 u) {
  union { unsigned int i; float f; } x; x.i = ((unsigned int)u) << 16; return x.f;
}
__device__ __forceinline__ u16 f2bf(float f) {
  union { float f; unsigned int i; } x; x.f = f;
  unsigned int r = x.i + 0x7FFFu + ((x.i >> 16) & 1u);  // RNE
  return (u16)(r >> 16);
}
__device__ __forceinline__ void split2(float v, u16& hi, u16& lo) {
  hi = f2bf(v);
  lo = f2bf(v - bf2f(hi));
}
__device__ __forceinline__ float gelu_f(float v) {
  return 0.5f * v * (1.0f + erff(v * 0.70710678118654752f));
}

// ---------------- fused prep: embed(split) + weight pack + Wf transpose -----
// blocks [0,800): h split ; [800,1964): pack ; [1964,2464): Wf transpose
__global__ __launch_bounds__(256) void k_prep(
    const int* __restrict__ x, const float* __restrict__ tok, const float* __restrict__ pos,
    const float* __restrict__ Wq, const float* __restrict__ Wk, const float* __restrict__ Wv,
    const float* __restrict__ bq, const float* __restrict__ bk, const float* __restrict__ bv,
    const float* __restrict__ Wo, const float* __restrict__ W1, const float* __restrict__ W2,
    const float* __restrict__ Wf,
    u16* __restrict__ hH, u16* __restrict__ hL,
    u16* __restrict__ WqkvTh, u16* __restrict__ WqkvTl, float* __restrict__ bqkv,
    u16* __restrict__ WoTh, u16* __restrict__ WoTl,
    u16* __restrict__ W1Th, u16* __restrict__ W1Tl,
    u16* __restrict__ W2Th, u16* __restrict__ W2Tl,
    u16* __restrict__ WfTh, u16* __restrict__ WfTl) {
  __shared__ __align__(16) float tile[64][68];
  int bid = blockIdx.x;
  if (bid < 800) {  // embed + split: h[row][e] = tok[x[row]][e] + pos[t][e]
    int i = bid * 256 + threadIdx.x;
    int row = i >> 6, e = i & 63;
    int t = row % T_;
    int v = x[row];
    split2(tok[(long)v * 64 + e] + pos[t * 64 + e], hH[i], hL[i]);
    return;
  }
  if (bid < 1964) {  // pack weights into split-bf16 B^T layouts
    int i = (bid - 800) * 256 + threadIdx.x;
    const int S0 = 196608, S1 = 3072, S2 = 65536, S3 = 16384;
    if (i < S0) {  // WqkvT[n][e] = W_p[head][e][d] ; n = p*1024 + head*128 + d
      int n = i >> 6, e = i & 63;
      int p = n >> 10, rem = n & 1023;
      int hh_ = rem >> 7, d = rem & 127;
      const float* W = (p == 0) ? Wq : ((p == 1) ? Wk : Wv);
      split2(W[hh_ * 8192 + e * 128 + d], WqkvTh[i], WqkvTl[i]);
      return;
    }
    i -= S0;
    if (i < S1) { int p = i >> 10, rem = i & 1023;
      const float* bb = (p == 0) ? bq : ((p == 1) ? bk : bv);
      bqkv[i] = bb[rem]; return; }
    i -= S1;
    if (i < S2) { int n = i >> 10, k = i & 1023;
      split2(Wo[k * 64 + n], WoTh[i], WoTl[i]); return; }
    i -= S2;
    if (i < S3) { int n = i >> 6, k = i & 63;
      split2(W1[k * 256 + n], W1Th[i], W1Tl[i]); return; }
    i -= S3;
    { int n = i >> 8, k = i & 255;
      split2(W2[k * 64 + n], W2Th[i], W2Tl[i]); }
    return;
  }
  // Wf [64][32000] f32 -> WfT hi/lo bf16 [32000][64]
  int n0 = (bid - 1964) * 64;
  for (int c = threadIdx.x; c < 1024; c += 256) {
    int k = c >> 4, ch = (c & 15) * 4;
    *(float4*)&tile[k][ch] = *(const float4*)&Wf[(long)k * 32000 + n0 + ch];
  }
  __syncthreads();
  for (int c = threadIdx.x; c < 1024; c += 256) {
    int n = c >> 4, ch = (c & 15) * 4;
    u16 th[4], tl[4];
#pragma unroll
    for (int j = 0; j < 4; ++j) split2(tile[ch + j][n], th[j], tl[j]);
    *(ushort4*)&WfTh[(long)(n0 + n) * 64 + ch] = *(ushort4*)th;
    *(ushort4*)&WfTl[(long)(n0 + n) * 64 + ch] = *(ushort4*)tl;
  }
}

// ---------------- attention: one block per (b,head), fp32, 4-row groups -----
// QKV f32 [3200][3072]: cols [0,1024)=Q, [1024,2048)=K, [2048,3072)=V
// K in LDS [64][128] f32 XOR-swizzled:  elem(s,d) at s*128 + ((d4^(s&31))<<2)+(d&3)
//   -> ds_read_b128 of row=lane, same logical col across lanes is conflict-free.
// V in LDS TRANSPOSED [128][64] swizzled: elem(d,s) at d*64 + ((s4^(d&15))<<2)+(s&3)
//   -> PV reads 4 consecutive s per b128, conflict-free across lanes (d=lane).
// Each wave processes 4 query rows per pass: K/V LDS traffic cut 4x.
__global__ __launch_bounds__(256) void k_attn(const float* __restrict__ QKV,
                                              u16* __restrict__ Oh,
                                              u16* __restrict__ Ol) {
  __shared__ __align__(16) float Kl[64 * 128];
  __shared__ __align__(16) float Vt[128 * 64];
  __shared__ __align__(16) float Qw[4][512];   // per-wave, 4 rows x 128
  __shared__ __align__(16) float Pw[4][256];   // per-wave, 4 rows x 64
  const int bh = blockIdx.x, b = bh >> 3, hd = bh & 7;
  const int tid = threadIdx.x, lane = tid & 63, wave = tid >> 6;
  const float* base = QKV + (long)b * T_ * 3072 + hd * 128;
  for (int c = tid; c < 64 * 32; c += 256) {
    int s = c >> 5, c4 = c & 31;
    float4 kv = make_float4(0.f, 0.f, 0.f, 0.f), vv = kv;  // zero rows 50..63
    if (s < T_) {
      const float* rowp = base + (long)s * 3072;
      kv = *(const float4*)(rowp + 1024 + c4 * 4);
      vv = *(const float4*)(rowp + 2048 + c4 * 4);
    }
    *(float4*)&Kl[s * 128 + ((c4 ^ (s & 31)) << 2)] = kv;
    int d0 = c4 * 4, s4 = s >> 2, sm = s & 3;
    Vt[(d0 + 0) * 64 + ((s4 ^ ((d0 + 0) & 15)) << 2) + sm] = vv.x;
    Vt[(d0 + 1) * 64 + ((s4 ^ ((d0 + 1) & 15)) << 2) + sm] = vv.y;
    Vt[(d0 + 2) * 64 + ((s4 ^ ((d0 + 2) & 15)) << 2) + sm] = vv.z;
    Vt[(d0 + 3) * 64 + ((s4 ^ ((d0 + 3) & 15)) << 2) + sm] = vv.w;
  }
  __syncthreads();
  const float scale = 0.0883883476483184406f;  // 1/sqrt(128)
  for (int g = wave; g < 13; g += 4) {         // group g = rows 4g..4g+3
    const int r0 = g * 4;
    // stage 4 Q rows into per-wave LDS (coalesced float4)
#pragma unroll
    for (int it = 0; it < 2; ++it) {
      int cc = lane + it * 64;
      int j = cc >> 5, c4q = cc & 31;
      int rq = r0 + j;
      if (rq < T_)
        *(float4*)&Qw[wave][j * 128 + c4q * 4] =
            *(const float4*)&base[(long)rq * 3072 + c4q * 4];
    }
    asm volatile("s_waitcnt lgkmcnt(0)" ::: "memory");  // wave-local Qw RAW
    // scores: lane owns s = lane; 4 rows in parallel, d ascending (same order
    // as previous kernel -> bitwise-identical softmax inputs)
    float p0 = 0.f, p1 = 0.f, p2 = 0.f, p3 = 0.f;
#pragma unroll 8
    for (int c4 = 0; c4 < 32; ++c4) {
      float4 kv = *(const float4*)&Kl[lane * 128 + ((c4 ^ (lane & 31)) << 2)];
      float4 q0 = *(const float4*)&Qw[wave][c4 * 4];
      float4 q1 = *(const float4*)&Qw[wave][128 + c4 * 4];
      float4 q2 = *(const float4*)&Qw[wave][256 + c4 * 4];
      float4 q3 = *(const float4*)&Qw[wave][384 + c4 * 4];
      p0 = fmaf(q0.x, kv.x, p0); p0 = fmaf(q0.y, kv.y, p0);
      p0 = fmaf(q0.z, kv.z, p0); p0 = fmaf(q0.w, kv.w, p0);
      p1 = fmaf(q1.x, kv.x, p1); p1 = fmaf(q1.y, kv.y, p1);
      p1 = fmaf(q1.z, kv.z, p1); p1 = fmaf(q1.w, kv.w, p1);
      p2 = fmaf(q2.x, kv.x, p2); p2 = fmaf(q2.y, kv.y, p2);
      p2 = fmaf(q2.z, kv.z, p2); p2 = fmaf(q2.w, kv.w, p2);
      p3 = fmaf(q3.x, kv.x, p3); p3 = fmaf(q3.y, kv.y, p3);
      p3 = fmaf(q3.z, kv.z, p3); p3 = fmaf(q3.w, kv.w, p3);
    }
    float ps[4] = {p0, p1, p2, p3};
#pragma unroll
    for (int j = 0; j < 4; ++j) {
      int rq = r0 + j;
      float sc = (rq < T_ && lane <= rq) ? ps[j] * scale : -INFINITY;
      float mx = sc;
      mx = fmaxf(mx, __shfl_xor(mx, 32)); mx = fmaxf(mx, __shfl_xor(mx, 16));
      mx = fmaxf(mx, __shfl_xor(mx, 8));  mx = fmaxf(mx, __shfl_xor(mx, 4));
      mx = fmaxf(mx, __shfl_xor(mx, 2));  mx = fmaxf(mx, __shfl_xor(mx, 1));
      float e = expf(sc - mx);  // masked lanes: exp(-inf) = 0
      float sum = e;
      sum += __shfl_xor(sum, 32); sum += __shfl_xor(sum, 16); sum += __shfl_xor(sum, 8);
      sum += __shfl_xor(sum, 4);  sum += __shfl_xor(sum, 2);  sum += __shfl_xor(sum, 1);
      Pw[wave][j * 64 + lane] = e / sum;  // rows >=50: NaN, never consumed
    }
    asm volatile("s_waitcnt lgkmcnt(0)" ::: "memory");  // wave-local Pw RAW
    // PV: s ascending (same order as before); V zero for s in [50,64)
    float oa[4] = {0.f, 0.f, 0.f, 0.f};  // d = lane
    float ob[4] = {0.f, 0.f, 0.f, 0.f};  // d = 64+lane
    for (int s4 = 0; s4 <= g; ++s4) {
      int vc = (s4 ^ (lane & 15)) << 2;
      float4 va = *(const float4*)&Vt[lane * 64 + vc];
      float4 vb = *(const float4*)&Vt[(64 + lane) * 64 + vc];
#pragma unroll
      for (int j = 0; j < 4; ++j) {
        float4 pb = *(const float4*)&Pw[wave][j * 64 + s4 * 4];
        oa[j] = fmaf(pb.x, va.x, oa[j]); oa[j] = fmaf(pb.y, va.y, oa[j]);
        oa[j] = fmaf(pb.z, va.z, oa[j]); oa[j] = fmaf(pb.w, va.w, oa[j]);
        ob[j] = fmaf(pb.x, vb.x, ob[j]); ob[j] = fmaf(pb.y, vb.y, ob[j]);
        ob[j] = fmaf(pb.z, vb.z, ob[j]); ob[j] = fmaf(pb.w, vb.w, ob[j]);
      }
    }
#pragma unroll
    for (int j = 0; j < 4; ++j) {
      int rq = r0 + j;
      if (rq < T_) {
        long orow = ((long)b * T_ + rq) * 1024 + hd * 128;
        u16 hi, lo;
        split2(oa[j], hi, lo); Oh[orow + lane] = hi;      Ol[orow + lane] = lo;
        split2(ob[j], hi, lo); Oh[orow + 64 + lane] = hi; Ol[orow + 64 + lane] = lo;
      }
    }
  }
}

// ------- split-precision MFMA GEMM, LDS-free, swapped-operand ---------------
// A pre-split bf16 hi/lo [M][KK]; Bt pre-split bf16 hi/lo [N][KK]; both frags
// fetched directly from global (panels are L2-resident at these shapes).
// SWAPPED operands: mfma(b, a) -> D row(quad*4+reg)=n, col(ln)=m. Thread holds
// 4 CONSECUTIVE output columns -> float4/ushort4 stores. Products commute and
// k-reduction tree is unchanged -> bitwise-identical to unswapped.
// SWZ: bijective 8-XCD chunk swizzle so each XCD's B working set is L2-fit.
template <int WM, int TN, int KK, int ACT, int OSPLIT, int SWZ>
__global__ __launch_bounds__(WM * 64) void k_gemm(
    const u16* __restrict__ Ah, const u16* __restrict__ Al,
    const u16* __restrict__ Bth, const u16* __restrict__ Btl,
    const float* __restrict__ bias,
    float* __restrict__ C, u16* __restrict__ Ch, u16* __restrict__ Cl,
    int ldc, int gm) {
  int id = blockIdx.x;
  if constexpr (SWZ) {
    int nbk = gridDim.x;
    int q = nbk >> 3, r = nbk & 7;
    int xcd = id & 7, idx = id >> 3;
    id = (xcd < r ? xcd * (q + 1) : r * (q + 1) + (xcd - r) * q) + idx;
  }
  const int mb = id % gm, nb = id / gm;
  const int m0 = mb * (WM * 16), n0 = nb * (TN * 16);
  const int tid = threadIdx.x, lane = tid & 63, wave = tid >> 6;
  const int ln = lane & 15, quad = lane >> 4;
  const int mrow = m0 + wave * 16 + ln;
  const long arow = (long)mrow * KK;
  f32x4 acc[TN];
#pragma unroll
  for (int tn = 0; tn < TN; ++tn)
#pragma unroll
    for (int i = 0; i < 4; ++i) acc[tn][i] = 0.f;
#pragma unroll
  for (int k0 = 0; k0 < KK; k0 += 32) {
    bf16x8 a_h = *(const bf16x8*)&Ah[arow + k0 + quad * 8];
    bf16x8 a_l = *(const bf16x8*)&Al[arow + k0 + quad * 8];
#pragma unroll
    for (int tn = 0; tn < TN; ++tn) {
      const long brow = (long)(n0 + tn * 16 + ln) * KK + k0 + quad * 8;
      bf16x8 b_h = *(const bf16x8*)&Bth[brow];
      bf16x8 b_l = *(const bf16x8*)&Btl[brow];
      acc[tn] = __builtin_amdgcn_mfma_f32_16x16x32_bf16(b_h, a_h, acc[tn], 0, 0, 0);
      acc[tn] = __builtin_amdgcn_mfma_f32_16x16x32_bf16(b_h, a_l, acc[tn], 0, 0, 0);
      acc[tn] = __builtin_amdgcn_mfma_f32_16x16x32_bf16(b_l, a_h, acc[tn], 0, 0, 0);
    }
  }
#pragma unroll
  for (int tn = 0; tn < TN; ++tn) {
    int nc = n0 + tn * 16 + quad * 4;
    float4 bv = *(const float4*)&bias[nc];
    float v0 = acc[tn][0] + bv.x, v1 = acc[tn][1] + bv.y;
    float v2 = acc[tn][2] + bv.z, v3 = acc[tn][3] + bv.w;
    if (ACT) { v0 = gelu_f(v0); v1 = gelu_f(v1); v2 = gelu_f(v2); v3 = gelu_f(v3); }
    long idx2 = (long)mrow * ldc + nc;
    if constexpr (OSPLIT) {
      ushort4 hs, ls;
      split2(v0, hs.x, ls.x); split2(v1, hs.y, ls.y);
      split2(v2, hs.z, ls.z); split2(v3, hs.w, ls.w);
      *(ushort4*)&Ch[idx2] = hs;
      *(ushort4*)&Cl[idx2] = ls;
    } else {
      *(float4*)&C[idx2] = make_float4(v0, v1, v2, v3);
    }
  }
}

// ---------------- fused MLP: y = gelu(o@Wo+bo @ W1+b1) @ W2 + b2 ------------
// One wave per 16 rows; intermediates a[16][64], m[16][256] split in LDS.
// Same k-order / split order as the separate GEMMs -> bitwise-identical.
__global__ __launch_bounds__(64) void k_mlp(
    const u16* __restrict__ oH, const u16* __restrict__ oL,
    const u16* __restrict__ WoTh, const u16* __restrict__ WoTl, const float* __restrict__ bo,
    const u16* __restrict__ W1Th, const u16* __restrict__ W1Tl, const float* __restrict__ b1,
    const u16* __restrict__ W2Th, const u16* __restrict__ W2Tl, const float* __restrict__ b2,
    u16* __restrict__ yH, u16* __restrict__ yL) {
  __shared__ __align__(16) u16 aLh[16][88], aLl[16][88];    // stride 176B (16-mult)
  __shared__ __align__(16) u16 mLh[16][264], mLl[16][264];  // stride 528B (16-mult)
  const int lane = threadIdx.x, ln = lane & 15, quad = lane >> 4;
  const int r = blockIdx.x * 16 + ln;
  // ---- GEMM1: a = o @ WoT^T + bo  (K=1024, N=64)
  f32x4 acc1[4];
#pragma unroll
  for (int tn = 0; tn < 4; ++tn)
#pragma unroll
    for (int i = 0; i < 4; ++i) acc1[tn][i] = 0.f;
#pragma unroll 4
  for (int k0 = 0; k0 < 1024; k0 += 32) {
    bf16x8 a_h = *(const bf16x8*)&oH[(long)r * 1024 + k0 + quad * 8];
    bf16x8 a_l = *(const bf16x8*)&oL[(long)r * 1024 + k0 + quad * 8];
#pragma unroll
    for (int tn = 0; tn < 4; ++tn) {
      const int brow = (tn * 16 + ln) * 1024 + k0 + quad * 8;
      bf16x8 b_h = *(const bf16x8*)&WoTh[brow];
      bf16x8 b_l = *(const bf16x8*)&WoTl[brow];
      acc1[tn] = __builtin_amdgcn_mfma_f32_16x16x32_bf16(b_h, a_h, acc1[tn], 0, 0, 0);
      acc1[tn] = __builtin_amdgcn_mfma_f32_16x16x32_bf16(b_h, a_l, acc1[tn], 0, 0, 0);
      acc1[tn] = __builtin_amdgcn_mfma_f32_16x16x32_bf16(b_l, a_h, acc1[tn], 0, 0, 0);
    }
  }
#pragma unroll
  for (int tn = 0; tn < 4; ++tn) {
    int nc = tn * 16 + quad * 4;
    float4 bv = *(const float4*)&bo[nc];
    ushort4 hs, ls;
    split2(acc1[tn][0] + bv.x, hs.x, ls.x); split2(acc1[tn][1] + bv.y, hs.y, ls.y);
    split2(acc1[tn][2] + bv.z, hs.z, ls.z); split2(acc1[tn][3] + bv.w, hs.w, ls.w);
    *(ushort4*)&aLh[ln][nc] = hs;
    *(ushort4*)&aLl[ln][nc] = ls;
  }
  __syncthreads();
  // ---- GEMM2: m = gelu(a @ W1T^T + b1)  (K=64, N=256)
  f32x4 acc2[16];
#pragma unroll
  for (int tn = 0; tn < 16; ++tn)
#pragma unroll
    for (int i = 0; i < 4; ++i) acc2[tn][i] = 0.f;
#pragma unroll
  for (int k0 = 0; k0 < 64; k0 += 32) {
    bf16x8 a_h = *(const bf16x8*)&aLh[ln][k0 + quad * 8];
    bf16x8 a_l = *(const bf16x8*)&aLl[ln][k0 + quad * 8];
#pragma unroll
    for (int tn = 0; tn < 16; ++tn) {
      const int brow = (tn * 16 + ln) * 64 + k0 + quad * 8;
      bf16x8 b_h = *(const bf16x8*)&W1Th[brow];
      bf16x8 b_l = *(const bf16x8*)&W1Tl[brow];
      acc2[tn] = __builtin_amdgcn_mfma_f32_16x16x32_bf16(b_h, a_h, acc2[tn], 0, 0, 0);
      acc2[tn] = __builtin_amdgcn_mfma_f32_16x16x32_bf16(b_h, a_l, acc2[tn], 0, 0, 0);
      acc2[tn] = __builtin_amdgcn_mfma_f32_16x16x32_bf16(b_l, a_h, acc2[tn], 0, 0, 0);
    }
  }
#pragma unroll
  for (int tn = 0; tn < 16; ++tn) {
    int nc = tn * 16 + quad * 4;
    float4 bv = *(const float4*)&b1[nc];
    ushort4 hs, ls;
    split2(gelu_f(acc2[tn][0] + bv.x), hs.x, ls.x);
    split2(gelu_f(acc2[tn][1] + bv.y), hs.y, ls.y);
    split2(gelu_f(acc2[tn][2] + bv.z), hs.z, ls.z);
    split2(gelu_f(acc2[tn][3] + bv.w), hs.w, ls.w);
    *(ushort4*)&mLh[ln][nc] = hs;
    *(ushort4*)&mLl[ln][nc] = ls;
  }
  __syncthreads();
  // ---- GEMM3: y = m @ W2T^T + b2  (K=256, N=64)
  f32x4 acc3[4];
#pragma unroll
  for (int tn = 0; tn < 4; ++tn)
#pragma unroll
    for (int i = 0; i < 4; ++i) acc3[tn][i] = 0.f;
#pragma unroll 2
  for (int k0 = 0; k0 < 256; k0 += 32) {
    bf16x8 a_h = *(const bf16x8*)&mLh[ln][k0 + quad * 8];
    bf16x8 a_l = *(const bf16x8*)&mLl[ln][k0 + quad * 8];
#pragma unroll
    for (int tn = 0; tn < 4; ++tn) {
      const int brow = (tn * 16 + ln) * 256 + k0 + quad * 8;
      bf16x8 b_h = *(const bf16x8*)&W2Th[brow];
      bf16x8 b_l = *(const bf16x8*)&W2Tl[brow];
      acc3[tn] = __builtin_amdgcn_mfma_f32_16x16x32_bf16(b_h, a_h, acc3[tn], 0, 0, 0);
      acc3[tn] = __builtin_amdgcn_mfma_f32_16x16x32_bf16(b_h, a_l, acc3[tn], 0, 0, 0);
      acc3[tn] = __builtin_amdgcn_mfma_f32_16x16x32_bf16(b_l, a_h, acc3[tn], 0, 0, 0);
    }
  }
#pragma unroll
  for (int tn = 0; tn < 4; ++tn) {
    int nc = tn * 16 + quad * 4;
    float4 bv = *(const float4*)&b2[nc];
    ushort4 hs, ls;
    split2(acc3[tn][0] + bv.x, hs.x, ls.x); split2(acc3[tn][1] + bv.y, hs.y, ls.y);
    split2(acc3[tn][2] + bv.z, hs.z, ls.z); split2(acc3[tn][3] + bv.w, hs.w, ls.w);
    *(ushort4*)&yH[(long)r * 64 + nc] = hs;
    *(ushort4*)&yL[(long)r * 64 + nc] = ls;
  }
}

extern "C" void kernel_launch(void* const* d_in, const int* in_sizes, int n_in,
                              void* d_out, int out_size, void* d_ws, size_t ws_size,
                              hipStream_t stream) {
  const int*   x   = (const int*)d_in[0];
  const float* tok = (const float*)d_in[1];
  const float* pos = (const float*)d_in[2];
  const float* Wq  = (const float*)d_in[3];
  const float* bq  = (const float*)d_in[4];
  const float* Wk  = (const float*)d_in[5];
  const float* bk  = (const float*)d_in[6];
  const float* Wv  = (const float*)d_in[7];
  const float* bv  = (const float*)d_in[8];
  const float* Wo  = (const float*)d_in[9];
  const float* bo  = (const float*)d_in[10];
  const float* W1  = (const float*)d_in[11];
  const float* b1  = (const float*)d_in[12];
  const float* W2  = (const float*)d_in[13];
  const float* b2  = (const float*)d_in[14];
  const float* Wf  = (const float*)d_in[15];
  const float* bfv = (const float*)d_in[16];

  char* ws = (char*)d_ws;
  float* QKV    = (float*)(ws + 0);          // 3200*3072 f32 = 39,321,600
  u16*   oH     = (u16*)(ws + 39321600);     // 3200*1024 u16
  u16*   oL     = (u16*)(ws + 45875200);
  u16*   hH     = (u16*)(ws + 52428800);     // 3200*64 u16
  u16*   hL     = (u16*)(ws + 52838400);
  u16*   yH     = (u16*)(ws + 53248000);     // 3200*64 u16
  u16*   yL     = (u16*)(ws + 53657600);
  u16*   WqkvTh = (u16*)(ws + 54067200);     // 3072*64
  u16*   WqkvTl = (u16*)(ws + 54460416);
  float* bqkv   = (float*)(ws + 54853632);   // 3072 f32
  u16*   WoTh   = (u16*)(ws + 54865920);     // 64*1024
  u16*   WoTl   = (u16*)(ws + 54996992);
  u16*   W1Th   = (u16*)(ws + 55128064);     // 256*64
  u16*   W1Tl   = (u16*)(ws + 55160832);
  u16*   W2Th   = (u16*)(ws + 55193600);     // 64*256
  u16*   W2Tl   = (u16*)(ws + 55226368);
  u16*   WfTh   = (u16*)(ws + 55259136);     // 32000*64
  u16*   WfTl   = (u16*)(ws + 59355136);     // end 63,451,136
  float* out    = (float*)d_out;

  k_prep<<<dim3(2464), 256, 0, stream>>>(x, tok, pos, Wq, Wk, Wv, bq, bk, bv,
      Wo, W1, W2, Wf, hH, hL, WqkvTh, WqkvTl, bqkv, WoTh, WoTl,
      W1Th, W1Tl, W2Th, W2Tl, WfTh, WfTl);
  // QKV: [3200,64] @ [64,3072] -> f32 (LDS-free, float4 stores)
  k_gemm<4, 8, 64, 0, 0, 0><<<dim3(1200), 256, 0, stream>>>(
      hH, hL, WqkvTh, WqkvTl, bqkv, QKV, nullptr, nullptr, 3072, 50);
  k_attn<<<dim3(512), 256, 0, stream>>>(QKV, oH, oL);
  // fused MLP: o -> a -> m -> y (split), 200 one-wave blocks
  k_mlp<<<dim3(200), 64, 0, stream>>>(oH, oL, WoTh, WoTl, bo,
      W1Th, W1Tl, b1, W2Th, W2Tl, b2, yH, yL);
  // Final: [3200,64] @ [64,32000] -> logits f32 (write-bound, XCD-swizzled)
  k_gemm<4, 8, 64, 0, 0, 1><<<dim3(12500), 256, 0, stream>>>(
      yH, yL, WfTh, WfTl, bfv, out, nullptr, nullptr, 32000, 50);
}

// Round 3
// 602.743 us; speedup vs baseline: 1.2159x; 1.2159x over previous
//
#include <hip/hip_runtime.h>
#include <math.h>

// B=64 T=50 V=32000 E=64 DH=128 H=8 M=256 ; rows R = B*T = 3200
#define T_ 50
#define R_ 3200

using u16 = unsigned short;
typedef __attribute__((ext_vector_type(8))) __bf16 bf16x8;
typedef __attribute__((ext_vector_type(4))) float f32x4;

__device__ __forceinline__ float bf2f(u16 u) {
  union { unsigned int i; float f; } x; x.i = ((unsigned int)u) << 16; return x.f;
}
__device__ __forceinline__ u16 f2bf(float f) {
  union { float f; unsigned int i; } x; x.f = f;
  unsigned int r = x.i + 0x7FFFu + ((x.i >> 16) & 1u);  // RNE
  return (u16)(r >> 16);
}
__device__ __forceinline__ void split2(float v, u16& hi, u16& lo) {
  hi = f2bf(v);
  lo = f2bf(v - bf2f(hi));
}
__device__ __forceinline__ float gelu_f(float v) {
  return 0.5f * v * (1.0f + erff(v * 0.70710678118654752f));
}

// ---------------- fused prep: embed(split) + weight pack + Wf transpose -----
// blocks [0,800): h split ; [800,1964): pack ; [1964,2464): Wf transpose
__global__ __launch_bounds__(256) void k_prep(
    const int* __restrict__ x, const float* __restrict__ tok, const float* __restrict__ pos,
    const float* __restrict__ Wq, const float* __restrict__ Wk, const float* __restrict__ Wv,
    const float* __restrict__ bq, const float* __restrict__ bk, const float* __restrict__ bv,
    const float* __restrict__ Wo, const float* __restrict__ W1, const float* __restrict__ W2,
    const float* __restrict__ Wf,
    u16* __restrict__ hH, u16* __restrict__ hL,
    u16* __restrict__ WqkvTh, u16* __restrict__ WqkvTl, float* __restrict__ bqkv,
    u16* __restrict__ WoTh, u16* __restrict__ WoTl,
    u16* __restrict__ W1Th, u16* __restrict__ W1Tl,
    u16* __restrict__ W2Th, u16* __restrict__ W2Tl,
    u16* __restrict__ WfTh, u16* __restrict__ WfTl) {
  __shared__ __align__(16) float tile[64][68];
  int bid = blockIdx.x;
  if (bid < 800) {  // embed + split: h[row][e] = tok[x[row]][e] + pos[t][e]
    int i = bid * 256 + threadIdx.x;
    int row = i >> 6, e = i & 63;
    int t = row % T_;
    int v = x[row];
    split2(tok[(long)v * 64 + e] + pos[t * 64 + e], hH[i], hL[i]);
    return;
  }
  if (bid < 1964) {  // pack weights into split-bf16 B^T layouts
    int i = (bid - 800) * 256 + threadIdx.x;
    const int S0 = 196608, S1 = 3072, S2 = 65536, S3 = 16384;
    if (i < S0) {  // WqkvT[n][e] = W_p[head][e][d] ; n = p*1024 + head*128 + d
      int n = i >> 6, e = i & 63;
      int p = n >> 10, rem = n & 1023;
      int hh_ = rem >> 7, d = rem & 127;
      const float* W = (p == 0) ? Wq : ((p == 1) ? Wk : Wv);
      split2(W[hh_ * 8192 + e * 128 + d], WqkvTh[i], WqkvTl[i]);
      return;
    }
    i -= S0;
    if (i < S1) { int p = i >> 10, rem = i & 1023;
      const float* bb = (p == 0) ? bq : ((p == 1) ? bk : bv);
      bqkv[i] = bb[rem]; return; }
    i -= S1;
    if (i < S2) { int n = i >> 10, k = i & 1023;
      split2(Wo[k * 64 + n], WoTh[i], WoTl[i]); return; }
    i -= S2;
    if (i < S3) { int n = i >> 6, k = i & 63;
      split2(W1[k * 256 + n], W1Th[i], W1Tl[i]); return; }
    i -= S3;
    { int n = i >> 8, k = i & 255;
      split2(W2[k * 64 + n], W2Th[i], W2Tl[i]); }
    return;
  }
  // Wf [64][32000] f32 -> WfT hi/lo bf16 [32000][64]
  int n0 = (bid - 1964) * 64;
  for (int c = threadIdx.x; c < 1024; c += 256) {
    int k = c >> 4, ch = (c & 15) * 4;
    *(float4*)&tile[k][ch] = *(const float4*)&Wf[(long)k * 32000 + n0 + ch];
  }
  __syncthreads();
  for (int c = threadIdx.x; c < 1024; c += 256) {
    int n = c >> 4, ch = (c & 15) * 4;
    u16 th[4], tl[4];
#pragma unroll
    for (int j = 0; j < 4; ++j) split2(tile[ch + j][n], th[j], tl[j]);
    *(ushort4*)&WfTh[(long)(n0 + n) * 64 + ch] = *(ushort4*)th;
    *(ushort4*)&WfTl[(long)(n0 + n) * 64 + ch] = *(ushort4*)tl;
  }
}

// ---------------- attention: one block per (b,head), fp32, 4-row groups -----
// (identical to R2's passing version; ~3x fewer LDS instrs than R1's)
__global__ __launch_bounds__(256) void k_attn(const float* __restrict__ QKV,
                                              u16* __restrict__ Oh,
                                              u16* __restrict__ Ol) {
  __shared__ __align__(16) float Kl[64 * 128];
  __shared__ __align__(16) float Vt[128 * 64];
  __shared__ __align__(16) float Qw[4][512];   // per-wave, 4 rows x 128
  __shared__ __align__(16) float Pw[4][256];   // per-wave, 4 rows x 64
  const int bh = blockIdx.x, b = bh >> 3, hd = bh & 7;
  const int tid = threadIdx.x, lane = tid & 63, wave = tid >> 6;
  const float* base = QKV + (long)b * T_ * 3072 + hd * 128;
  for (int c = tid; c < 64 * 32; c += 256) {
    int s = c >> 5, c4 = c & 31;
    float4 kv = make_float4(0.f, 0.f, 0.f, 0.f), vv = kv;  // zero rows 50..63
    if (s < T_) {
      const float* rowp = base + (long)s * 3072;
      kv = *(const float4*)(rowp + 1024 + c4 * 4);
      vv = *(const float4*)(rowp + 2048 + c4 * 4);
    }
    *(float4*)&Kl[s * 128 + ((c4 ^ (s & 31)) << 2)] = kv;
    int d0 = c4 * 4, s4 = s >> 2, sm = s & 3;
    Vt[(d0 + 0) * 64 + ((s4 ^ ((d0 + 0) & 15)) << 2) + sm] = vv.x;
    Vt[(d0 + 1) * 64 + ((s4 ^ ((d0 + 1) & 15)) << 2) + sm] = vv.y;
    Vt[(d0 + 2) * 64 + ((s4 ^ ((d0 + 2) & 15)) << 2) + sm] = vv.z;
    Vt[(d0 + 3) * 64 + ((s4 ^ ((d0 + 3) & 15)) << 2) + sm] = vv.w;
  }
  __syncthreads();
  const float scale = 0.0883883476483184406f;  // 1/sqrt(128)
  for (int g = wave; g < 13; g += 4) {         // group g = rows 4g..4g+3
    const int r0 = g * 4;
#pragma unroll
    for (int it = 0; it < 2; ++it) {
      int cc = lane + it * 64;
      int j = cc >> 5, c4q = cc & 31;
      int rq = r0 + j;
      if (rq < T_)
        *(float4*)&Qw[wave][j * 128 + c4q * 4] =
            *(const float4*)&base[(long)rq * 3072 + c4q * 4];
    }
    asm volatile("s_waitcnt lgkmcnt(0)" ::: "memory");  // wave-local Qw RAW
    float p0 = 0.f, p1 = 0.f, p2 = 0.f, p3 = 0.f;
#pragma unroll 8
    for (int c4 = 0; c4 < 32; ++c4) {
      float4 kv = *(const float4*)&Kl[lane * 128 + ((c4 ^ (lane & 31)) << 2)];
      float4 q0 = *(const float4*)&Qw[wave][c4 * 4];
      float4 q1 = *(const float4*)&Qw[wave][128 + c4 * 4];
      float4 q2 = *(const float4*)&Qw[wave][256 + c4 * 4];
      float4 q3 = *(const float4*)&Qw[wave][384 + c4 * 4];
      p0 = fmaf(q0.x, kv.x, p0); p0 = fmaf(q0.y, kv.y, p0);
      p0 = fmaf(q0.z, kv.z, p0); p0 = fmaf(q0.w, kv.w, p0);
      p1 = fmaf(q1.x, kv.x, p1); p1 = fmaf(q1.y, kv.y, p1);
      p1 = fmaf(q1.z, kv.z, p1); p1 = fmaf(q1.w, kv.w, p1);
      p2 = fmaf(q2.x, kv.x, p2); p2 = fmaf(q2.y, kv.y, p2);
      p2 = fmaf(q2.z, kv.z, p2); p2 = fmaf(q2.w, kv.w, p2);
      p3 = fmaf(q3.x, kv.x, p3); p3 = fmaf(q3.y, kv.y, p3);
      p3 = fmaf(q3.z, kv.z, p3); p3 = fmaf(q3.w, kv.w, p3);
    }
    float ps[4] = {p0, p1, p2, p3};
#pragma unroll
    for (int j = 0; j < 4; ++j) {
      int rq = r0 + j;
      float sc = (rq < T_ && lane <= rq) ? ps[j] * scale : -INFINITY;
      float mx = sc;
      mx = fmaxf(mx, __shfl_xor(mx, 32)); mx = fmaxf(mx, __shfl_xor(mx, 16));
      mx = fmaxf(mx, __shfl_xor(mx, 8));  mx = fmaxf(mx, __shfl_xor(mx, 4));
      mx = fmaxf(mx, __shfl_xor(mx, 2));  mx = fmaxf(mx, __shfl_xor(mx, 1));
      float e = expf(sc - mx);  // masked lanes: exp(-inf) = 0
      float sum = e;
      sum += __shfl_xor(sum, 32); sum += __shfl_xor(sum, 16); sum += __shfl_xor(sum, 8);
      sum += __shfl_xor(sum, 4);  sum += __shfl_xor(sum, 2);  sum += __shfl_xor(sum, 1);
      Pw[wave][j * 64 + lane] = e / sum;  // rows >=50: NaN, never consumed
    }
    asm volatile("s_waitcnt lgkmcnt(0)" ::: "memory");  // wave-local Pw RAW
    float oa[4] = {0.f, 0.f, 0.f, 0.f};  // d = lane
    float ob[4] = {0.f, 0.f, 0.f, 0.f};  // d = 64+lane
    for (int s4 = 0; s4 <= g; ++s4) {
      int vc = (s4 ^ (lane & 15)) << 2;
      float4 va = *(const float4*)&Vt[lane * 64 + vc];
      float4 vb = *(const float4*)&Vt[(64 + lane) * 64 + vc];
#pragma unroll
      for (int j = 0; j < 4; ++j) {
        float4 pb = *(const float4*)&Pw[wave][j * 64 + s4 * 4];
        oa[j] = fmaf(pb.x, va.x, oa[j]); oa[j] = fmaf(pb.y, va.y, oa[j]);
        oa[j] = fmaf(pb.z, va.z, oa[j]); oa[j] = fmaf(pb.w, va.w, oa[j]);
        ob[j] = fmaf(pb.x, vb.x, ob[j]); ob[j] = fmaf(pb.y, vb.y, ob[j]);
        ob[j] = fmaf(pb.z, vb.z, ob[j]); ob[j] = fmaf(pb.w, vb.w, ob[j]);
      }
    }
#pragma unroll
    for (int j = 0; j < 4; ++j) {
      int rq = r0 + j;
      if (rq < T_) {
        long orow = ((long)b * T_ + rq) * 1024 + hd * 128;
        u16 hi, lo;
        split2(oa[j], hi, lo); Oh[orow + lane] = hi;      Ol[orow + lane] = lo;
        split2(ob[j], hi, lo); Oh[orow + 64 + lane] = hi; Ol[orow + 64 + lane] = lo;
      }
    }
  }
}

// ------- split-precision MFMA GEMM: C = A @ Bt^T + bias ---------------------
// R1-proven structure: B pre-split bf16 staged in LDS (+8 u16 pad, bank-quad
// uniform); A pre-split bf16 fetched direct from global (rows wave-exclusive).
// SWAPPED operands mfma(b,a): D row=n (quad*4+reg), col=m (ln) -> each thread
// holds 4 consecutive output columns: float4/ushort4 stores + float4 bias.
// Products commute, per-slot sum tree unchanged -> bitwise-identical.
// D = ah*bh + al*bh + ah*bl  (al*bl ~ 2^-18 rel, dropped).
// SWZ: bijective 8-XCD chunk swizzle (final GEMM only; id m-fastest so a
// chunk spans ~31 n-panels -> ~1 MB WfT working set per XCD, L2-fit).
template <int BN, int BK, int ACT, int OSPLIT, int SWZ>
__global__ __launch_bounds__(256) void k_gemm(
    const u16* __restrict__ Ah, const u16* __restrict__ Al,
    const u16* __restrict__ Bth, const u16* __restrict__ Btl,
    const float* __restrict__ bias,
    float* __restrict__ C, u16* __restrict__ Ch, u16* __restrict__ Cl,
    int ldc, int K, int gm) {
  constexpr int BM = 64;
  constexpr int TN = BN / 16;
  constexpr int BKW = BK / 8;
  __shared__ __align__(16) u16 Bh[BN][BK + 8];
  __shared__ __align__(16) u16 Bl[BN][BK + 8];
  int id = blockIdx.x;
  if constexpr (SWZ) {
    int nbk = gridDim.x;
    int q = nbk >> 3, r = nbk & 7;
    int xcd = id & 7, idx = id >> 3;
    id = (xcd < r ? xcd * (q + 1) : r * (q + 1) + (xcd - r) * q) + idx;
  }
  const int m0 = (id % gm) * BM, n0 = (id / gm) * BN;
  const int tid = threadIdx.x, lane = tid & 63, wave = tid >> 6;
  const int ln = lane & 15, quad = lane >> 4;
  const int mrow = m0 + wave * 16 + ln;
  const long arow = (long)mrow * K;
  f32x4 acc[TN];
#pragma unroll
  for (int tn = 0; tn < TN; ++tn)
#pragma unroll
    for (int i = 0; i < 4; ++i) acc[tn][i] = 0.f;

  for (int kk = 0; kk < K; kk += BK) {
#pragma unroll
    for (int c0 = 0; c0 < BN * BKW; c0 += 256) {
      int c = c0 + tid;
      int rr = c / BKW, c8 = (c % BKW) * 8;
      *(uint4*)&Bh[rr][c8] = *(const uint4*)&Bth[(long)(n0 + rr) * K + kk + c8];
      *(uint4*)&Bl[rr][c8] = *(const uint4*)&Btl[(long)(n0 + rr) * K + kk + c8];
    }
    __syncthreads();
#pragma unroll
    for (int ks = 0; ks < BK / 32; ++ks) {
      bf16x8 a_h = *(const bf16x8*)&Ah[arow + kk + ks * 32 + quad * 8];
      bf16x8 a_l = *(const bf16x8*)&Al[arow + kk + ks * 32 + quad * 8];
#pragma unroll
      for (int tn = 0; tn < TN; ++tn) {
        bf16x8 b_h = *(const bf16x8*)&Bh[tn * 16 + ln][ks * 32 + quad * 8];
        bf16x8 b_l = *(const bf16x8*)&Bl[tn * 16 + ln][ks * 32 + quad * 8];
        acc[tn] = __builtin_amdgcn_mfma_f32_16x16x32_bf16(b_h, a_h, acc[tn], 0, 0, 0);
        acc[tn] = __builtin_amdgcn_mfma_f32_16x16x32_bf16(b_h, a_l, acc[tn], 0, 0, 0);
        acc[tn] = __builtin_amdgcn_mfma_f32_16x16x32_bf16(b_l, a_h, acc[tn], 0, 0, 0);
      }
    }
    __syncthreads();
  }
#pragma unroll
  for (int tn = 0; tn < TN; ++tn) {
    int nc = n0 + tn * 16 + quad * 4;
    float4 bv = *(const float4*)&bias[nc];
    float v0 = acc[tn][0] + bv.x, v1 = acc[tn][1] + bv.y;
    float v2 = acc[tn][2] + bv.z, v3 = acc[tn][3] + bv.w;
    if (ACT) { v0 = gelu_f(v0); v1 = gelu_f(v1); v2 = gelu_f(v2); v3 = gelu_f(v3); }
    long idx2 = (long)mrow * ldc + nc;
    if constexpr (OSPLIT) {
      ushort4 hs, ls;
      split2(v0, hs.x, ls.x); split2(v1, hs.y, ls.y);
      split2(v2, hs.z, ls.z); split2(v3, hs.w, ls.w);
      *(ushort4*)&Ch[idx2] = hs;
      *(ushort4*)&Cl[idx2] = ls;
    } else {
      *(float4*)&C[idx2] = make_float4(v0, v1, v2, v3);
    }
  }
}

extern "C" void kernel_launch(void* const* d_in, const int* in_sizes, int n_in,
                              void* d_out, int out_size, void* d_ws, size_t ws_size,
                              hipStream_t stream) {
  const int*   x   = (const int*)d_in[0];
  const float* tok = (const float*)d_in[1];
  const float* pos = (const float*)d_in[2];
  const float* Wq  = (const float*)d_in[3];
  const float* bq  = (const float*)d_in[4];
  const float* Wk  = (const float*)d_in[5];
  const float* bk  = (const float*)d_in[6];
  const float* Wv  = (const float*)d_in[7];
  const float* bv  = (const float*)d_in[8];
  const float* Wo  = (const float*)d_in[9];
  const float* bo  = (const float*)d_in[10];
  const float* W1  = (const float*)d_in[11];
  const float* b1  = (const float*)d_in[12];
  const float* W2  = (const float*)d_in[13];
  const float* b2  = (const float*)d_in[14];
  const float* Wf  = (const float*)d_in[15];
  const float* bfv = (const float*)d_in[16];

  char* ws = (char*)d_ws;
  float* QKV    = (float*)(ws + 0);          // 3200*3072 f32 = 39,321,600
  u16*   oH     = (u16*)(ws + 39321600);     // 3200*1024 u16
  u16*   oL     = (u16*)(ws + 45875200);
  u16*   hH     = (u16*)(ws + 52428800);     // 3200*64 u16
  u16*   hL     = (u16*)(ws + 52838400);
  u16*   aH     = (u16*)(ws + 53248000);     // 3200*64 u16
  u16*   aL     = (u16*)(ws + 53657600);
  u16*   mH     = (u16*)(ws + 54067200);     // 3200*256 u16
  u16*   mL     = (u16*)(ws + 55705600);
  u16*   yH     = (u16*)(ws + 57344000);     // 3200*64 u16
  u16*   yL     = (u16*)(ws + 57753600);
  u16*   WqkvTh = (u16*)(ws + 58163200);     // 3072*64
  u16*   WqkvTl = (u16*)(ws + 58556416);
  float* bqkv   = (float*)(ws + 58949632);   // 3072 f32
  u16*   WoTh   = (u16*)(ws + 58961920);     // 64*1024
  u16*   WoTl   = (u16*)(ws + 59092992);
  u16*   W1Th   = (u16*)(ws + 59224064);     // 256*64
  u16*   W1Tl   = (u16*)(ws + 59256832);
  u16*   W2Th   = (u16*)(ws + 59289600);     // 64*256
  u16*   W2Tl   = (u16*)(ws + 59322368);
  u16*   WfTh   = (u16*)(ws + 59355136);     // 32000*64
  u16*   WfTl   = (u16*)(ws + 63451136);     // end 67,547,136
  float* out    = (float*)d_out;

  k_prep<<<dim3(2464), 256, 0, stream>>>(x, tok, pos, Wq, Wk, Wv, bq, bk, bv,
      Wo, W1, W2, Wf, hH, hL, WqkvTh, WqkvTl, bqkv, WoTh, WoTl,
      W1Th, W1Tl, W2Th, W2Tl, WfTh, WfTl);
  // QKV: [3200,64] @ [64,3072] -> f32
  k_gemm<128, 64, 0, 0, 0><<<dim3(1200), 256, 0, stream>>>(
      hH, hL, WqkvTh, WqkvTl, bqkv, QKV, nullptr, nullptr, 3072, 64, 50);
  k_attn<<<dim3(512), 256, 0, stream>>>(QKV, oH, oL);
  // Wo: [3200,1024] @ [1024,64] -> split a
  k_gemm<64, 256, 0, 1, 0><<<dim3(50), 256, 0, stream>>>(
      oH, oL, WoTh, WoTl, bo, nullptr, aH, aL, 64, 1024, 50);
  // FFN1 + exact GELU: [3200,64] @ [64,256] -> split m
  k_gemm<128, 64, 1, 1, 0><<<dim3(100), 256, 0, stream>>>(
      aH, aL, W1Th, W1Tl, b1, nullptr, mH, mL, 256, 64, 50);
  // FFN2: [3200,256] @ [256,64] -> split y
  k_gemm<64, 256, 0, 1, 0><<<dim3(50), 256, 0, stream>>>(
      mH, mL, W2Th, W2Tl, b2, nullptr, yH, yL, 64, 256, 50);
  // Final: [3200,64] @ [64,32000] -> logits f32 (write-bound, XCD-swizzled)
  k_gemm<128, 64, 0, 0, 1><<<dim3(12500), 256, 0, stream>>>(
      yH, yL, WfTh, WfTl, bfv, out, nullptr, nullptr, 32000, 64, 50);
}

// Round 4
// 600.273 us; speedup vs baseline: 1.2209x; 1.0041x over previous
//
#include <hip/hip_runtime.h>
#include <math.h>

// B=64 T=50 V=32000 E=64 DH=128 H=8 M=256 ; rows R = B*T = 3200
#define T_ 50
#define R_ 3200

using u16 = unsigned short;
typedef __attribute__((ext_vector_type(8))) __bf16 bf16x8;
typedef __attribute__((ext_vector_type(4))) float f32x4;

__device__ __forceinline__ float bf2f(u16 u) {
  union { unsigned int i; float f; } x; x.i = ((unsigned int)u) << 16; return x.f;
}
__device__ __forceinline__ u16 f2bf(float f) {
  union { float f; unsigned int i; } x; x.f = f;
  unsigned int r = x.i + 0x7FFFu + ((x.i >> 16) & 1u);  // RNE
  return (u16)(r >> 16);
}
__device__ __forceinline__ void split2(float v, u16& hi, u16& lo) {
  hi = f2bf(v);
  lo = f2bf(v - bf2f(hi));
}
__device__ __forceinline__ float gelu_f(float v) {
  return 0.5f * v * (1.0f + erff(v * 0.70710678118654752f));
}

// ---------------- fused prep: embed(split) + weight pack + Wf transpose -----
// blocks [0,800): h split ; [800,1964): pack ; [1964,2464): Wf transpose
__global__ __launch_bounds__(256) void k_prep(
    const int* __restrict__ x, const float* __restrict__ tok, const float* __restrict__ pos,
    const float* __restrict__ Wq, const float* __restrict__ Wk, const float* __restrict__ Wv,
    const float* __restrict__ bq, const float* __restrict__ bk, const float* __restrict__ bv,
    const float* __restrict__ Wo, const float* __restrict__ W1, const float* __restrict__ W2,
    const float* __restrict__ Wf,
    u16* __restrict__ hH, u16* __restrict__ hL,
    u16* __restrict__ WqkvTh, u16* __restrict__ WqkvTl, float* __restrict__ bqkv,
    u16* __restrict__ WoTh, u16* __restrict__ WoTl,
    u16* __restrict__ W1Th, u16* __restrict__ W1Tl,
    u16* __restrict__ W2Th, u16* __restrict__ W2Tl,
    u16* __restrict__ WfTh, u16* __restrict__ WfTl) {
  __shared__ __align__(16) float tile[64][68];
  int bid = blockIdx.x;
  if (bid < 800) {  // embed + split: h[row][e] = tok[x[row]][e] + pos[t][e]
    int i = bid * 256 + threadIdx.x;
    int row = i >> 6, e = i & 63;
    int t = row % T_;
    int v = x[row];
    split2(tok[(long)v * 64 + e] + pos[t * 64 + e], hH[i], hL[i]);
    return;
  }
  if (bid < 1964) {  // pack weights into split-bf16 B^T layouts
    int i = (bid - 800) * 256 + threadIdx.x;
    const int S0 = 196608, S1 = 3072, S2 = 65536, S3 = 16384;
    if (i < S0) {  // WqkvT[n][e] = W_p[head][e][d] ; n = p*1024 + head*128 + d
      int n = i >> 6, e = i & 63;
      int p = n >> 10, rem = n & 1023;
      int hh_ = rem >> 7, d = rem & 127;
      const float* W = (p == 0) ? Wq : ((p == 1) ? Wk : Wv);
      split2(W[hh_ * 8192 + e * 128 + d], WqkvTh[i], WqkvTl[i]);
      return;
    }
    i -= S0;
    if (i < S1) { int p = i >> 10, rem = i & 1023;
      const float* bb = (p == 0) ? bq : ((p == 1) ? bk : bv);
      bqkv[i] = bb[rem]; return; }
    i -= S1;
    if (i < S2) { int n = i >> 10, k = i & 1023;
      split2(Wo[k * 64 + n], WoTh[i], WoTl[i]); return; }
    i -= S2;
    if (i < S3) { int n = i >> 6, k = i & 63;
      split2(W1[k * 256 + n], W1Th[i], W1Tl[i]); return; }
    i -= S3;
    { int n = i >> 8, k = i & 255;
      split2(W2[k * 64 + n], W2Th[i], W2Tl[i]); }
    return;
  }
  // Wf [64][32000] f32 -> WfT hi/lo bf16 [32000][64]
  int n0 = (bid - 1964) * 64;
  for (int c = threadIdx.x; c < 1024; c += 256) {
    int k = c >> 4, ch = (c & 15) * 4;
    *(float4*)&tile[k][ch] = *(const float4*)&Wf[(long)k * 32000 + n0 + ch];
  }
  __syncthreads();
  for (int c = threadIdx.x; c < 1024; c += 256) {
    int n = c >> 4, ch = (c & 15) * 4;
    u16 th[4], tl[4];
#pragma unroll
    for (int j = 0; j < 4; ++j) split2(tile[ch + j][n], th[j], tl[j]);
    *(ushort4*)&WfTh[(long)(n0 + n) * 64 + ch] = *(ushort4*)th;
    *(ushort4*)&WfTl[(long)(n0 + n) * 64 + ch] = *(ushort4*)tl;
  }
}

// ------- fused QKV projection + attention: one block per (b,head) ----------
// Phase 1: compute this block's Q,K,V tile via MFMA (bitwise-identical to the
// old standalone QKV GEMM: same 3-mfma triple, same k-order 0,32; bias after).
// D layout (swapped mfma(b,a)): thread (wave,ln,quad) holds, for tile t,
// n = t*16 + quad*4 + r, m = wave*16 + ln (row b*50+m of h, padded alloc).
// Results go straight to LDS: Q f32 rows; K swizzled [64][128]; V transposed+
// swizzled [128][64] with rows s>=50 zeroed (consumed by PV). K/Q rows >=50
// may be garbage/NaN -- masked to -inf in scores, never consumed.
// Phase 2: identical score/softmax/PV code as R3 (Q read from LDS).
__global__ __launch_bounds__(256) void k_attn(
    const u16* __restrict__ hH, const u16* __restrict__ hL,
    const u16* __restrict__ WqkvTh, const u16* __restrict__ WqkvTl,
    const float* __restrict__ bqkv,
    u16* __restrict__ Oh, u16* __restrict__ Ol) {
  __shared__ __align__(16) float Kl[64 * 128];
  __shared__ __align__(16) float Vt[128 * 64];
  __shared__ __align__(16) float Qall[64][132];   // stride 132: 2-way banks
  __shared__ __align__(16) float Pw[4][256];
  const int bh = blockIdx.x, b = bh >> 3, hd = bh & 7;
  const int tid = threadIdx.x, lane = tid & 63, wave = tid >> 6;
  const int ln = lane & 15, quad = lane >> 4;
  const int m = wave * 16 + ln;
  // ---- phase 1: QKV projection ----
  const long arow = ((long)b * T_ + m) * 64;  // h row (alloc padded to 3264)
  f32x4 acc[24];
#pragma unroll
  for (int t = 0; t < 24; ++t)
#pragma unroll
    for (int i = 0; i < 4; ++i) acc[t][i] = 0.f;
#pragma unroll
  for (int ks = 0; ks < 2; ++ks) {
    bf16x8 a_h = *(const bf16x8*)&hH[arow + ks * 32 + quad * 8];
    bf16x8 a_l = *(const bf16x8*)&hL[arow + ks * 32 + quad * 8];
#pragma unroll
    for (int t = 0; t < 24; ++t) {
      const long brow =
          (long)((t >> 3) * 1024 + hd * 128 + (t & 7) * 16 + ln) * 64 + ks * 32 + quad * 8;
      bf16x8 b_h = *(const bf16x8*)&WqkvTh[brow];
      bf16x8 b_l = *(const bf16x8*)&WqkvTl[brow];
      acc[t] = __builtin_amdgcn_mfma_f32_16x16x32_bf16(b_h, a_h, acc[t], 0, 0, 0);
      acc[t] = __builtin_amdgcn_mfma_f32_16x16x32_bf16(b_h, a_l, acc[t], 0, 0, 0);
      acc[t] = __builtin_amdgcn_mfma_f32_16x16x32_bf16(b_l, a_h, acc[t], 0, 0, 0);
    }
  }
  // Q rows -> Qall[m][n]
#pragma unroll
  for (int t = 0; t < 8; ++t) {
    float4 bv = *(const float4*)&bqkv[hd * 128 + t * 16 + quad * 4];
    *(float4*)&Qall[m][t * 16 + quad * 4] = make_float4(
        acc[t][0] + bv.x, acc[t][1] + bv.y, acc[t][2] + bv.z, acc[t][3] + bv.w);
  }
  // K -> Kl swizzled (elem(s,d) at s*128 + ((d4^(s&31))<<2)+(d&3))
#pragma unroll
  for (int t = 0; t < 8; ++t) {
    float4 bv = *(const float4*)&bqkv[1024 + hd * 128 + t * 16 + quad * 4];
    int c4 = t * 4 + quad;  // d>>2 (d&3 spans the float4)
    *(float4*)&Kl[m * 128 + ((c4 ^ (m & 31)) << 2)] = make_float4(
        acc[8 + t][0] + bv.x, acc[8 + t][1] + bv.y,
        acc[8 + t][2] + bv.z, acc[8 + t][3] + bv.w);
  }
  // V -> Vt transposed+swizzled (elem(d,s) at d*64 + ((s4^(d&15))<<2)+(s&3))
#pragma unroll
  for (int t = 0; t < 8; ++t) {
    float4 bv = *(const float4*)&bqkv[2048 + hd * 128 + t * 16 + quad * 4];
    float v0 = acc[16 + t][0] + bv.x, v1 = acc[16 + t][1] + bv.y;
    float v2 = acc[16 + t][2] + bv.z, v3 = acc[16 + t][3] + bv.w;
    if (m >= T_) { v0 = 0.f; v1 = 0.f; v2 = 0.f; v3 = 0.f; }  // s>=50: zero
    int d0 = t * 16 + quad * 4;
    int s4 = m >> 2, sm = m & 3;
    Vt[(d0 + 0) * 64 + ((s4 ^ ((d0 + 0) & 15)) << 2) + sm] = v0;
    Vt[(d0 + 1) * 64 + ((s4 ^ ((d0 + 1) & 15)) << 2) + sm] = v1;
    Vt[(d0 + 2) * 64 + ((s4 ^ ((d0 + 2) & 15)) << 2) + sm] = v2;
    Vt[(d0 + 3) * 64 + ((s4 ^ ((d0 + 3) & 15)) << 2) + sm] = v3;
  }
  __syncthreads();
  // ---- phase 2: attention (identical math/order to R3) ----
  const float scale = 0.0883883476483184406f;  // 1/sqrt(128)
  for (int g = wave; g < 13; g += 4) {  // group g = rows 4g..4g+3
    const int r0 = g * 4;
    float p0 = 0.f, p1 = 0.f, p2 = 0.f, p3 = 0.f;
#pragma unroll 8
    for (int c4 = 0; c4 < 32; ++c4) {
      float4 kv = *(const float4*)&Kl[lane * 128 + ((c4 ^ (lane & 31)) << 2)];
      float4 q0 = *(const float4*)&Qall[r0 + 0][c4 * 4];
      float4 q1 = *(const float4*)&Qall[r0 + 1][c4 * 4];
      float4 q2 = *(const float4*)&Qall[r0 + 2][c4 * 4];
      float4 q3 = *(const float4*)&Qall[r0 + 3][c4 * 4];
      p0 = fmaf(q0.x, kv.x, p0); p0 = fmaf(q0.y, kv.y, p0);
      p0 = fmaf(q0.z, kv.z, p0); p0 = fmaf(q0.w, kv.w, p0);
      p1 = fmaf(q1.x, kv.x, p1); p1 = fmaf(q1.y, kv.y, p1);
      p1 = fmaf(q1.z, kv.z, p1); p1 = fmaf(q1.w, kv.w, p1);
      p2 = fmaf(q2.x, kv.x, p2); p2 = fmaf(q2.y, kv.y, p2);
      p2 = fmaf(q2.z, kv.z, p2); p2 = fmaf(q2.w, kv.w, p2);
      p3 = fmaf(q3.x, kv.x, p3); p3 = fmaf(q3.y, kv.y, p3);
      p3 = fmaf(q3.z, kv.z, p3); p3 = fmaf(q3.w, kv.w, p3);
    }
    float ps[4] = {p0, p1, p2, p3};
#pragma unroll
    for (int j = 0; j < 4; ++j) {
      int rq = r0 + j;
      float sc = (rq < T_ && lane <= rq) ? ps[j] * scale : -INFINITY;
      float mx = sc;
      mx = fmaxf(mx, __shfl_xor(mx, 32)); mx = fmaxf(mx, __shfl_xor(mx, 16));
      mx = fmaxf(mx, __shfl_xor(mx, 8));  mx = fmaxf(mx, __shfl_xor(mx, 4));
      mx = fmaxf(mx, __shfl_xor(mx, 2));  mx = fmaxf(mx, __shfl_xor(mx, 1));
      float e = expf(sc - mx);  // masked lanes: exp(-inf) = 0
      float sum = e;
      sum += __shfl_xor(sum, 32); sum += __shfl_xor(sum, 16); sum += __shfl_xor(sum, 8);
      sum += __shfl_xor(sum, 4);  sum += __shfl_xor(sum, 2);  sum += __shfl_xor(sum, 1);
      Pw[wave][j * 64 + lane] = e / sum;  // rows >=50: NaN, never consumed
    }
    asm volatile("s_waitcnt lgkmcnt(0)" ::: "memory");  // wave-local Pw RAW
    float oa[4] = {0.f, 0.f, 0.f, 0.f};  // d = lane
    float ob[4] = {0.f, 0.f, 0.f, 0.f};  // d = 64+lane
    for (int s4 = 0; s4 <= g; ++s4) {
      int vc = (s4 ^ (lane & 15)) << 2;
      float4 va = *(const float4*)&Vt[lane * 64 + vc];
      float4 vb = *(const float4*)&Vt[(64 + lane) * 64 + vc];
#pragma unroll
      for (int j = 0; j < 4; ++j) {
        float4 pb = *(const float4*)&Pw[wave][j * 64 + s4 * 4];
        oa[j] = fmaf(pb.x, va.x, oa[j]); oa[j] = fmaf(pb.y, va.y, oa[j]);
        oa[j] = fmaf(pb.z, va.z, oa[j]); oa[j] = fmaf(pb.w, va.w, oa[j]);
        ob[j] = fmaf(pb.x, vb.x, ob[j]); ob[j] = fmaf(pb.y, vb.y, ob[j]);
        ob[j] = fmaf(pb.z, vb.z, ob[j]); ob[j] = fmaf(pb.w, vb.w, ob[j]);
      }
    }
#pragma unroll
    for (int j = 0; j < 4; ++j) {
      int rq = r0 + j;
      if (rq < T_) {
        long orow = ((long)b * T_ + rq) * 1024 + hd * 128;
        u16 hi, lo;
        split2(oa[j], hi, lo); Oh[orow + lane] = hi;      Ol[orow + lane] = lo;
        split2(ob[j], hi, lo); Oh[orow + 64 + lane] = hi; Ol[orow + 64 + lane] = lo;
      }
    }
  }
}

// ---------------- fused MLP: y = (gelu((o@Wo+bo)@W1+b1))@W2 + b2 ------------
// 200 blocks x 4 waves; block owns 16 rows; waves split N each stage.
// A-frags direct from global/LDS (ln-indexed rows); B direct from global
// (L2-resident). Sequential k-order + identical 3-mfma triple + identical
// split2 routing -> bitwise-identical to R3's three separate GEMMs.
__global__ __launch_bounds__(256) void k_mlp(
    const u16* __restrict__ oH, const u16* __restrict__ oL,
    const u16* __restrict__ WoTh, const u16* __restrict__ WoTl, const float* __restrict__ bo,
    const u16* __restrict__ W1Th, const u16* __restrict__ W1Tl, const float* __restrict__ b1,
    const u16* __restrict__ W2Th, const u16* __restrict__ W2Tl, const float* __restrict__ b2,
    u16* __restrict__ yH, u16* __restrict__ yL) {
  __shared__ __align__(16) u16 aLh[16][72], aLl[16][72];    // 144B stride
  __shared__ __align__(16) u16 mLh[16][272], mLl[16][272];  // 544B stride
  const int tid = threadIdx.x, lane = tid & 63, wave = tid >> 6;
  const int ln = lane & 15, quad = lane >> 4;
  const long r = (long)blockIdx.x * 16 + ln;  // global row for this lane
  // ---- stage 1: a = o @ WoT^T + bo   (K=1024, N=64; wave w -> cols 16w..)
  f32x4 acc1;
#pragma unroll
  for (int i = 0; i < 4; ++i) acc1[i] = 0.f;
#pragma unroll 4
  for (int k0 = 0; k0 < 1024; k0 += 32) {
    bf16x8 a_h = *(const bf16x8*)&oH[r * 1024 + k0 + quad * 8];
    bf16x8 a_l = *(const bf16x8*)&oL[r * 1024 + k0 + quad * 8];
    const int brow = (wave * 16 + ln) * 1024 + k0 + quad * 8;
    bf16x8 b_h = *(const bf16x8*)&WoTh[brow];
    bf16x8 b_l = *(const bf16x8*)&WoTl[brow];
    acc1 = __builtin_amdgcn_mfma_f32_16x16x32_bf16(b_h, a_h, acc1, 0, 0, 0);
    acc1 = __builtin_amdgcn_mfma_f32_16x16x32_bf16(b_h, a_l, acc1, 0, 0, 0);
    acc1 = __builtin_amdgcn_mfma_f32_16x16x32_bf16(b_l, a_h, acc1, 0, 0, 0);
  }
  {
    int nc = wave * 16 + quad * 4;
    float4 bv = *(const float4*)&bo[nc];
    ushort4 hs, ls;
    split2(acc1[0] + bv.x, hs.x, ls.x); split2(acc1[1] + bv.y, hs.y, ls.y);
    split2(acc1[2] + bv.z, hs.z, ls.z); split2(acc1[3] + bv.w, hs.w, ls.w);
    *(ushort4*)&aLh[ln][nc] = hs;  // D col=m=ln -> row ln, cols nc..nc+3
    *(ushort4*)&aLl[ln][nc] = ls;
  }
  __syncthreads();
  // ---- stage 2: m = gelu(a @ W1T^T + b1)  (K=64, N=256; wave w -> 64 cols)
  f32x4 acc2[4];
#pragma unroll
  for (int t = 0; t < 4; ++t)
#pragma unroll
    for (int i = 0; i < 4; ++i) acc2[t][i] = 0.f;
#pragma unroll
  for (int k0 = 0; k0 < 64; k0 += 32) {
    bf16x8 a_h = *(const bf16x8*)&aLh[ln][k0 + quad * 8];
    bf16x8 a_l = *(const bf16x8*)&aLl[ln][k0 + quad * 8];
#pragma unroll
    for (int t = 0; t < 4; ++t) {
      const int brow = (wave * 64 + t * 16 + ln) * 64 + k0 + quad * 8;
      bf16x8 b_h = *(const bf16x8*)&W1Th[brow];
      bf16x8 b_l = *(const bf16x8*)&W1Tl[brow];
      acc2[t] = __builtin_amdgcn_mfma_f32_16x16x32_bf16(b_h, a_h, acc2[t], 0, 0, 0);
      acc2[t] = __builtin_amdgcn_mfma_f32_16x16x32_bf16(b_h, a_l, acc2[t], 0, 0, 0);
      acc2[t] = __builtin_amdgcn_mfma_f32_16x16x32_bf16(b_l, a_h, acc2[t], 0, 0, 0);
    }
  }
#pragma unroll
  for (int t = 0; t < 4; ++t) {
    int nc = wave * 64 + t * 16 + quad * 4;
    float4 bv = *(const float4*)&b1[nc];
    ushort4 hs, ls;
    split2(gelu_f(acc2[t][0] + bv.x), hs.x, ls.x);
    split2(gelu_f(acc2[t][1] + bv.y), hs.y, ls.y);
    split2(gelu_f(acc2[t][2] + bv.z), hs.z, ls.z);
    split2(gelu_f(acc2[t][3] + bv.w), hs.w, ls.w);
    *(ushort4*)&mLh[ln][nc] = hs;
    *(ushort4*)&mLl[ln][nc] = ls;
  }
  __syncthreads();
  // ---- stage 3: y = m @ W2T^T + b2   (K=256, N=64; wave w -> cols 16w..)
  f32x4 acc3;
#pragma unroll
  for (int i = 0; i < 4; ++i) acc3[i] = 0.f;
#pragma unroll 2
  for (int k0 = 0; k0 < 256; k0 += 32) {
    bf16x8 a_h = *(const bf16x8*)&mLh[ln][k0 + quad * 8];
    bf16x8 a_l = *(const bf16x8*)&mLl[ln][k0 + quad * 8];
    const int brow = (wave * 16 + ln) * 256 + k0 + quad * 8;
    bf16x8 b_h = *(const bf16x8*)&W2Th[brow];
    bf16x8 b_l = *(const bf16x8*)&W2Tl[brow];
    acc3 = __builtin_amdgcn_mfma_f32_16x16x32_bf16(b_h, a_h, acc3, 0, 0, 0);
    acc3 = __builtin_amdgcn_mfma_f32_16x16x32_bf16(b_h, a_l, acc3, 0, 0, 0);
    acc3 = __builtin_amdgcn_mfma_f32_16x16x32_bf16(b_l, a_h, acc3, 0, 0, 0);
  }
  {
    int nc = wave * 16 + quad * 4;
    float4 bv = *(const float4*)&b2[nc];
    ushort4 hs, ls;
    split2(acc3[0] + bv.x, hs.x, ls.x); split2(acc3[1] + bv.y, hs.y, ls.y);
    split2(acc3[2] + bv.z, hs.z, ls.z); split2(acc3[3] + bv.w, hs.w, ls.w);
    *(ushort4*)&yH[r * 64 + nc] = hs;
    *(ushort4*)&yL[r * 64 + nc] = ls;
  }
}

// ------- split-precision MFMA GEMM (final logits only), as R3 ---------------
template <int BN, int BK, int ACT, int OSPLIT, int SWZ>
__global__ __launch_bounds__(256) void k_gemm(
    const u16* __restrict__ Ah, const u16* __restrict__ Al,
    const u16* __restrict__ Bth, const u16* __restrict__ Btl,
    const float* __restrict__ bias,
    float* __restrict__ C, u16* __restrict__ Ch, u16* __restrict__ Cl,
    int ldc, int K, int gm) {
  constexpr int BM = 64;
  constexpr int TN = BN / 16;
  constexpr int BKW = BK / 8;
  __shared__ __align__(16) u16 Bh[BN][BK + 8];
  __shared__ __align__(16) u16 Bl[BN][BK + 8];
  int id = blockIdx.x;
  if constexpr (SWZ) {
    int nbk = gridDim.x;
    int q = nbk >> 3, r = nbk & 7;
    int xcd = id & 7, idx = id >> 3;
    id = (xcd < r ? xcd * (q + 1) : r * (q + 1) + (xcd - r) * q) + idx;
  }
  const int m0 = (id % gm) * BM, n0 = (id / gm) * BN;
  const int tid = threadIdx.x, lane = tid & 63, wave = tid >> 6;
  const int ln = lane & 15, quad = lane >> 4;
  const int mrow = m0 + wave * 16 + ln;
  const long arow = (long)mrow * K;
  f32x4 acc[TN];
#pragma unroll
  for (int tn = 0; tn < TN; ++tn)
#pragma unroll
    for (int i = 0; i < 4; ++i) acc[tn][i] = 0.f;

  for (int kk = 0; kk < K; kk += BK) {
#pragma unroll
    for (int c0 = 0; c0 < BN * BKW; c0 += 256) {
      int c = c0 + tid;
      int rr = c / BKW, c8 = (c % BKW) * 8;
      *(uint4*)&Bh[rr][c8] = *(const uint4*)&Bth[(long)(n0 + rr) * K + kk + c8];
      *(uint4*)&Bl[rr][c8] = *(const uint4*)&Btl[(long)(n0 + rr) * K + kk + c8];
    }
    __syncthreads();
#pragma unroll
    for (int ks = 0; ks < BK / 32; ++ks) {
      bf16x8 a_h = *(const bf16x8*)&Ah[arow + kk + ks * 32 + quad * 8];
      bf16x8 a_l = *(const bf16x8*)&Al[arow + kk + ks * 32 + quad * 8];
#pragma unroll
      for (int tn = 0; tn < TN; ++tn) {
        bf16x8 b_h = *(const bf16x8*)&Bh[tn * 16 + ln][ks * 32 + quad * 8];
        bf16x8 b_l = *(const bf16x8*)&Bl[tn * 16 + ln][ks * 32 + quad * 8];
        acc[tn] = __builtin_amdgcn_mfma_f32_16x16x32_bf16(b_h, a_h, acc[tn], 0, 0, 0);
        acc[tn] = __builtin_amdgcn_mfma_f32_16x16x32_bf16(b_h, a_l, acc[tn], 0, 0, 0);
        acc[tn] = __builtin_amdgcn_mfma_f32_16x16x32_bf16(b_l, a_h, acc[tn], 0, 0, 0);
      }
    }
    __syncthreads();
  }
#pragma unroll
  for (int tn = 0; tn < TN; ++tn) {
    int nc = n0 + tn * 16 + quad * 4;
    float4 bv = *(const float4*)&bias[nc];
    float v0 = acc[tn][0] + bv.x, v1 = acc[tn][1] + bv.y;
    float v2 = acc[tn][2] + bv.z, v3 = acc[tn][3] + bv.w;
    if (ACT) { v0 = gelu_f(v0); v1 = gelu_f(v1); v2 = gelu_f(v2); v3 = gelu_f(v3); }
    long idx2 = (long)mrow * ldc + nc;
    if constexpr (OSPLIT) {
      ushort4 hs, ls;
      split2(v0, hs.x, ls.x); split2(v1, hs.y, ls.y);
      split2(v2, hs.z, ls.z); split2(v3, hs.w, ls.w);
      *(ushort4*)&Ch[idx2] = hs;
      *(ushort4*)&Cl[idx2] = ls;
    } else {
      *(float4*)&C[idx2] = make_float4(v0, v1, v2, v3);
    }
  }
}

extern "C" void kernel_launch(void* const* d_in, const int* in_sizes, int n_in,
                              void* d_out, int out_size, void* d_ws, size_t ws_size,
                              hipStream_t stream) {
  const int*   x   = (const int*)d_in[0];
  const float* tok = (const float*)d_in[1];
  const float* pos = (const float*)d_in[2];
  const float* Wq  = (const float*)d_in[3];
  const float* bq  = (const float*)d_in[4];
  const float* Wk  = (const float*)d_in[5];
  const float* bk  = (const float*)d_in[6];
  const float* Wv  = (const float*)d_in[7];
  const float* bv  = (const float*)d_in[8];
  const float* Wo  = (const float*)d_in[9];
  const float* bo  = (const float*)d_in[10];
  const float* W1  = (const float*)d_in[11];
  const float* b1  = (const float*)d_in[12];
  const float* W2  = (const float*)d_in[13];
  const float* b2  = (const float*)d_in[14];
  const float* Wf  = (const float*)d_in[15];
  const float* bfv = (const float*)d_in[16];

  char* ws = (char*)d_ws;
  u16*   hH     = (u16*)(ws + 0);            // 3264 rows x 64 (64-row pad)
  u16*   hL     = (u16*)(ws + 417792);
  u16*   oH     = (u16*)(ws + 835584);       // 3200*1024 u16
  u16*   oL     = (u16*)(ws + 7389184);
  u16*   yH     = (u16*)(ws + 13942784);     // 3200*64 u16
  u16*   yL     = (u16*)(ws + 14352384);
  u16*   WqkvTh = (u16*)(ws + 14761984);     // 3072*64
  u16*   WqkvTl = (u16*)(ws + 15155200);
  float* bqkv   = (float*)(ws + 15548416);   // 3072 f32
  u16*   WoTh   = (u16*)(ws + 15560704);     // 64*1024
  u16*   WoTl   = (u16*)(ws + 15691776);
  u16*   W1Th   = (u16*)(ws + 15822848);     // 256*64
  u16*   W1Tl   = (u16*)(ws + 15855616);
  u16*   W2Th   = (u16*)(ws + 15888384);     // 64*256
  u16*   W2Tl   = (u16*)(ws + 15921152);
  u16*   WfTh   = (u16*)(ws + 15953920);     // 32000*64
  u16*   WfTl   = (u16*)(ws + 20049920);     // end 24,145,920
  float* out    = (float*)d_out;

  k_prep<<<dim3(2464), 256, 0, stream>>>(x, tok, pos, Wq, Wk, Wv, bq, bk, bv,
      Wo, W1, W2, Wf, hH, hL, WqkvTh, WqkvTl, bqkv, WoTh, WoTl,
      W1Th, W1Tl, W2Th, W2Tl, WfTh, WfTl);
  // fused QKV projection + attention: one block per (b,head)
  k_attn<<<dim3(512), 256, 0, stream>>>(hH, hL, WqkvTh, WqkvTl, bqkv, oH, oL);
  // fused MLP: o -> a -> gelu -> y (split), 200 blocks x 4 waves
  k_mlp<<<dim3(200), 256, 0, stream>>>(oH, oL, WoTh, WoTl, bo,
      W1Th, W1Tl, b1, W2Th, W2Tl, b2, yH, yL);
  // Final: [3200,64] @ [64,32000] -> logits f32 (write-bound, XCD-swizzled)
  k_gemm<128, 64, 0, 0, 1><<<dim3(12500), 256, 0, stream>>>(
      yH, yL, WfTh, WfTl, bfv, out, nullptr, nullptr, 32000, 64, 50);
}